// Round 6
// baseline (194.356 us; speedup 1.0000x reference)
//
#include <hip/hip_runtime.h>
#include <hip/hip_bf16.h>

#define LROWS 50000
#define KNN 32
#define DIM 128
#define TAU_INV 5.0f
#define EPS_NORM 1e-8f
#define TILE 32
#define ROWSTR 136  // LDS row stride in shorts (272 B): bank-shift 4/row, 16B-aligned

typedef short s8v __attribute__((ext_vector_type(8)));
typedef float f32x4 __attribute__((ext_vector_type(4)));
typedef float f32x2 __attribute__((ext_vector_type(2)));
typedef int i32x4 __attribute__((ext_vector_type(4)));

__device__ __forceinline__ unsigned short f2bf(float f) {
  union { float f; unsigned u; } v; v.f = f;
  unsigned r = v.u + 0x7FFFu + ((v.u >> 16) & 1u);
  return (unsigned short)(r >> 16);
}
__device__ __forceinline__ float bf2f(short s) {
  union { unsigned u; float f; } v;
  v.u = ((unsigned)(unsigned short)s) << 16;
  return v.f;
}

// ---------------------------------------------------------------------------
// Kernel A: Mt[c][k] = (Wq^T Wk)^T[c][k] = sum_j Wk[j][c] * Wq[j][k], bf16.
// ---------------------------------------------------------------------------
__global__ __launch_bounds__(128) void mmat_kernel(
    const float* __restrict__ Wq, const float* __restrict__ Wk,
    unsigned short* __restrict__ Mt) {
  const int c = blockIdx.x;
  const int k = threadIdx.x;
  float acc = 0.f;
#pragma unroll 8
  for (int j = 0; j < DIM; ++j)
    acc = fmaf(Wk[j * DIM + c], Wq[j * DIM + k], acc);
  Mt[c * DIM + k] = f2bf(acc);
}

// ---------------------------------------------------------------------------
// Kernel B: Hb8 = fp8_e4m3(H), elementwise. 1.6M threads x 4 floats -> 1 dword.
// ---------------------------------------------------------------------------
__global__ __launch_bounds__(256) void cvt8_kernel(
    const float* __restrict__ H, unsigned* __restrict__ Hb8) {
  const int t = blockIdx.x * 256 + threadIdx.x;
  const float4 a = ((const float4*)H)[t];
  unsigned d = 0;
  d = __builtin_amdgcn_cvt_pk_fp8_f32(a.x, a.y, d, false);
  d = __builtin_amdgcn_cvt_pk_fp8_f32(a.z, a.w, d, true);
  Hb8[t] = d;
}

// ---------------------------------------------------------------------------
// Kernel C (fused): per 32-row tile:
//   phase A: stage H tile bf16 in LDS -> G tile = H @ M via MFMA -> G bf16 LDS
//   phase C: sim = <G[l], fp8 Hb8[idx]>, softmax(K=32), mix, norm, COO emit.
// G never touches HBM. Hb8 gathers are 1 cache line each (128 B).
// ---------------------------------------------------------------------------
__global__ __launch_bounds__(256, 4) void fused_kernel(
    const float* __restrict__ H, const unsigned short* __restrict__ Mt,
    const unsigned char* __restrict__ Hb8, const float* __restrict__ mixp,
    const float* __restrict__ knn_w, const int* __restrict__ knn_idx,
    float* __restrict__ vals, float* __restrict__ rows,
    float* __restrict__ cols) {
  __shared__ short Hs[TILE * ROWSTR];  // 8.7 KB: H-tile bf16, then G-tile bf16
  const int tid = threadIdx.x;
  const int row0 = blockIdx.x * TILE;
  const int nrows = min(TILE, LROWS - row0);

  // ---- stage H tile as bf16 (512 chunks of 8 elems; 2 per thread) ----
#pragma unroll
  for (int i = 0; i < 2; ++i) {
    const int cid = i * 256 + tid;
    const int r = cid >> 4;
    const int cc = (cid & 15) * 8;
    const int gr = (r < nrows) ? r : 0;  // clamp OOB source rows (tail)
    const float4* src = (const float4*)(H + (size_t)(row0 + gr) * DIM + cc);
    const float4 a = src[0], b = src[1];
    s8v p;
    p[0] = (short)f2bf(a.x); p[1] = (short)f2bf(a.y);
    p[2] = (short)f2bf(a.z); p[3] = (short)f2bf(a.w);
    p[4] = (short)f2bf(b.x); p[5] = (short)f2bf(b.y);
    p[6] = (short)f2bf(b.z); p[7] = (short)f2bf(b.w);
    *(s8v*)&Hs[r * ROWSTR + cc] = p;
  }
  __syncthreads();

  const int lane = tid & 63;
  const int wv = tid >> 6;
  const int col0 = wv * 32;
  const int lr = lane & 15;
  const int lg = lane >> 4;

  // B-frags from Mt (row-major [c][k] = B[k][c] fragments), L2-hot.
  s8v bfrag[2][4];
#pragma unroll
  for (int nt = 0; nt < 2; ++nt)
#pragma unroll
    for (int kk = 0; kk < 4; ++kk)
      bfrag[nt][kk] =
          *(const s8v*)(Mt + (size_t)(col0 + nt * 16 + lr) * DIM + kk * 32 + lg * 8);

  f32x4 acc[2][2];
#pragma unroll
  for (int rt = 0; rt < 2; ++rt)
#pragma unroll
    for (int nt = 0; nt < 2; ++nt)
      acc[rt][nt] = (f32x4){0.f, 0.f, 0.f, 0.f};

#pragma unroll
  for (int rt = 0; rt < 2; ++rt)
#pragma unroll
    for (int kk = 0; kk < 4; ++kk) {
      const s8v afrag =
          *(const s8v*)&Hs[(rt * 16 + lr) * ROWSTR + kk * 32 + lg * 8];
#pragma unroll
      for (int nt = 0; nt < 2; ++nt)
        acc[rt][nt] = __builtin_amdgcn_mfma_f32_16x16x32_bf16(
            afrag, bfrag[nt][kk], acc[rt][nt], 0, 0, 0);
    }
  __syncthreads();  // all Hs reads done

  // ---- write G tile (bf16) back into Hs ----
#pragma unroll
  for (int rt = 0; rt < 2; ++rt)
#pragma unroll
    for (int nt = 0; nt < 2; ++nt)
#pragma unroll
      for (int i = 0; i < 4; ++i)
        Hs[(rt * 16 + lg * 4 + i) * ROWSTR + col0 + nt * 16 + lr] =
            (short)f2bf(acc[rt][nt][i]);
  __syncthreads();

  // ---- attn phase: 4 passes x 8 rows; 32 lanes per row ----
  const float beta = 1.0f / (1.0f + expf(-mixp[0]));
  const int k = tid & 31;
  const int rg = tid >> 5;
  for (int p = 0; p < TILE / 8; ++p) {
    const int rl = p * 8 + rg;  // uniform within each 32-lane group
    if (rl >= nrows) continue;
    const int l = row0 + rl;
    const int o = l * KNN + k;
    const int idx = __builtin_nontemporal_load(&knn_idx[o]);
    const float w_in = __builtin_nontemporal_load(&knn_w[o]);
    const i32x4* k16 = (const i32x4*)(Hb8 + (size_t)idx * DIM);
    const short* grow = &Hs[rl * ROWSTR];

    float s_acc = 0.f;
#pragma unroll
    for (int j = 0; j < 8; ++j) {  // 8 chunks of 16 elements
      const i32x4 c = k16[j];
      const s8v g0 = *(const s8v*)&grow[j * 16];
      const s8v g1 = *(const s8v*)&grow[j * 16 + 8];
      f32x2 lo, hi;
      lo = __builtin_amdgcn_cvt_pk_f32_fp8((unsigned)c[0], false);
      hi = __builtin_amdgcn_cvt_pk_f32_fp8((unsigned)c[0], true);
      s_acc = fmaf(bf2f(g0[0]), lo[0], s_acc);
      s_acc = fmaf(bf2f(g0[1]), lo[1], s_acc);
      s_acc = fmaf(bf2f(g0[2]), hi[0], s_acc);
      s_acc = fmaf(bf2f(g0[3]), hi[1], s_acc);
      lo = __builtin_amdgcn_cvt_pk_f32_fp8((unsigned)c[1], false);
      hi = __builtin_amdgcn_cvt_pk_f32_fp8((unsigned)c[1], true);
      s_acc = fmaf(bf2f(g0[4]), lo[0], s_acc);
      s_acc = fmaf(bf2f(g0[5]), lo[1], s_acc);
      s_acc = fmaf(bf2f(g0[6]), hi[0], s_acc);
      s_acc = fmaf(bf2f(g0[7]), hi[1], s_acc);
      lo = __builtin_amdgcn_cvt_pk_f32_fp8((unsigned)c[2], false);
      hi = __builtin_amdgcn_cvt_pk_f32_fp8((unsigned)c[2], true);
      s_acc = fmaf(bf2f(g1[0]), lo[0], s_acc);
      s_acc = fmaf(bf2f(g1[1]), lo[1], s_acc);
      s_acc = fmaf(bf2f(g1[2]), hi[0], s_acc);
      s_acc = fmaf(bf2f(g1[3]), hi[1], s_acc);
      lo = __builtin_amdgcn_cvt_pk_f32_fp8((unsigned)c[3], false);
      hi = __builtin_amdgcn_cvt_pk_f32_fp8((unsigned)c[3], true);
      s_acc = fmaf(bf2f(g1[4]), lo[0], s_acc);
      s_acc = fmaf(bf2f(g1[5]), lo[1], s_acc);
      s_acc = fmaf(bf2f(g1[6]), hi[0], s_acc);
      s_acc = fmaf(bf2f(g1[7]), hi[1], s_acc);
    }
    const float sim = s_acc * TAU_INV;

    float m = sim;
#pragma unroll
    for (int off = 16; off > 0; off >>= 1)
      m = fmaxf(m, __shfl_xor(m, off, 32));
    const float e = expf(sim - m);
    float s = e;
#pragma unroll
    for (int off = 16; off > 0; off >>= 1)
      s += __shfl_xor(s, off, 32);
    const float A = e / s;

    float w = (1.0f - beta) * w_in + beta * A;
    float ws = w;
#pragma unroll
    for (int off = 16; off > 0; off >>= 1)
      ws += __shfl_xor(ws, off, 32);
    const float v = w / (ws + EPS_NORM);

    __builtin_nontemporal_store(v, &vals[o]);
    __builtin_nontemporal_store((float)l, &rows[o]);
    __builtin_nontemporal_store((float)idx, &cols[o]);
  }
}

extern "C" void kernel_launch(void* const* d_in, const int* in_sizes, int n_in,
                              void* d_out, int out_size, void* d_ws, size_t ws_size,
                              hipStream_t stream) {
  const float* H = (const float*)d_in[0];
  const float* Wq = (const float*)d_in[1];
  const float* Wk = (const float*)d_in[2];
  const float* mix = (const float*)d_in[3];
  const float* knn_w = (const float*)d_in[4];
  const int* knn_idx = (const int*)d_in[5];

  unsigned char* Hb8 = (unsigned char*)d_ws;                     // 6.4 MB
  unsigned short* Mt =
      (unsigned short*)((char*)d_ws + (size_t)LROWS * DIM);      // 32 KB

  float* out = (float*)d_out;
  float* vals = out;
  float* rowsp = out + (size_t)LROWS * KNN;
  float* colsp = out + 2 * (size_t)LROWS * KNN;

  mmat_kernel<<<DIM, DIM, 0, stream>>>(Wq, Wk, Mt);
  cvt8_kernel<<<(LROWS * DIM / 4) / 256, 256, 0, stream>>>(H, (unsigned*)Hb8);
  fused_kernel<<<(LROWS + TILE - 1) / TILE, 256, 0, stream>>>(
      H, Mt, Hb8, mix, knn_w, knn_idx, vals, rowsp, colsp);
}

// Round 8
// 126.488 us; speedup vs baseline: 1.5366x; 1.5366x over previous
//
#include <hip/hip_runtime.h>
#include <hip/hip_bf16.h>

#define LROWS 50000
#define KNN 32
#define DIM 128
#define TAU_INV 5.0f
#define EPS_NORM 1e-8f
#define ROWSTR 136  // proj LDS row stride in shorts (272 B): 2-way bank alias only

typedef short s8v __attribute__((ext_vector_type(8)));
typedef float f32x4 __attribute__((ext_vector_type(4)));
typedef float f32x2 __attribute__((ext_vector_type(2)));
typedef int i32x2 __attribute__((ext_vector_type(2)));
typedef int i32x4 __attribute__((ext_vector_type(4)));

__device__ __forceinline__ unsigned short f2bf(float f) {
  union { float f; unsigned u; } v; v.f = f;
  unsigned r = v.u + 0x7FFFu + ((v.u >> 16) & 1u);
  return (unsigned short)(r >> 16);
}
__device__ __forceinline__ float bf2f(short s) {
  union { unsigned u; float f; } v;
  v.u = ((unsigned)(unsigned short)s) << 16;
  return v.f;
}

// ---------------------------------------------------------------------------
// Kernel A: Mt[c][k] = (Wq^T Wk)^T[c][k] = sum_j Wk[j][c] * Wq[j][k], bf16.
// ---------------------------------------------------------------------------
__global__ __launch_bounds__(128) void mmat_kernel(
    const float* __restrict__ Wq, const float* __restrict__ Wk,
    unsigned short* __restrict__ Mt) {
  const int c = blockIdx.x;
  const int k = threadIdx.x;
  float acc = 0.f;
#pragma unroll 8
  for (int j = 0; j < DIM; ++j)
    acc = fmaf(Wk[j * DIM + c], Wq[j * DIM + k], acc);
  Mt[c * DIM + k] = f2bf(acc);
}

// ---------------------------------------------------------------------------
// Kernel B: Gb = bf16(H @ M) via MFMA 16x16x32 bf16; emits Hb8 = fp8_e4m3(H).
// Block = 256 thr (4 waves), 64 H-rows staged bf16 in LDS (17.4 KB, padded).
// ---------------------------------------------------------------------------
__global__ __launch_bounds__(256) void proj_kernel(
    const float* __restrict__ H, const unsigned short* __restrict__ Mt,
    unsigned short* __restrict__ Gb, unsigned char* __restrict__ Hb8) {
  __shared__ short Hs[64 * ROWSTR];
  const int tid = threadIdx.x;
  const int row0 = blockIdx.x * 64;
  const int nrows = min(64, LROWS - row0);

  // Stage H tile -> bf16 LDS (padded rows) + fp8 Hb8 global.
#pragma unroll
  for (int i = 0; i < 4; ++i) {
    const int cid = i * 256 + tid;   // 1024 chunks of 8 elems
    const int r = cid >> 4;          // local row 0..63
    const int cc = (cid & 15) * 8;   // col 0..120
    const int gr = (r < nrows) ? r : 0;
    const float4* src = (const float4*)(H + (size_t)(row0 + gr) * DIM + cc);
    const float4 a = src[0], b = src[1];
    s8v p;
    p[0] = (short)f2bf(a.x); p[1] = (short)f2bf(a.y);
    p[2] = (short)f2bf(a.z); p[3] = (short)f2bf(a.w);
    p[4] = (short)f2bf(b.x); p[5] = (short)f2bf(b.y);
    p[6] = (short)f2bf(b.z); p[7] = (short)f2bf(b.w);
    *(s8v*)&Hs[r * ROWSTR + cc] = p;
    if (r < nrows) {
      unsigned d0 = 0, d1 = 0;
      d0 = __builtin_amdgcn_cvt_pk_fp8_f32(a.x, a.y, d0, false);
      d0 = __builtin_amdgcn_cvt_pk_fp8_f32(a.z, a.w, d0, true);
      d1 = __builtin_amdgcn_cvt_pk_fp8_f32(b.x, b.y, d1, false);
      d1 = __builtin_amdgcn_cvt_pk_fp8_f32(b.z, b.w, d1, true);
      i32x2 pk; pk[0] = (int)d0; pk[1] = (int)d1;
      *(i32x2*)(Hb8 + (size_t)(row0 + r) * DIM + cc) = pk;
    }
  }
  __syncthreads();

  const int lane = tid & 63;
  const int wv = tid >> 6;
  const int col0 = wv * 32;
  const int lr = lane & 15;
  const int lg = lane >> 4;

  s8v bfrag[2][4];
#pragma unroll
  for (int nt = 0; nt < 2; ++nt)
#pragma unroll
    for (int kk = 0; kk < 4; ++kk)
      bfrag[nt][kk] =
          *(const s8v*)(Mt + (size_t)(col0 + nt * 16 + lr) * DIM + kk * 32 + lg * 8);

  f32x4 acc[4][2];
#pragma unroll
  for (int rt = 0; rt < 4; ++rt)
#pragma unroll
    for (int nt = 0; nt < 2; ++nt)
      acc[rt][nt] = (f32x4){0.f, 0.f, 0.f, 0.f};

#pragma unroll
  for (int rt = 0; rt < 4; ++rt)
#pragma unroll
    for (int kk = 0; kk < 4; ++kk) {
      const s8v afrag =
          *(const s8v*)&Hs[(rt * 16 + lr) * ROWSTR + kk * 32 + lg * 8];
#pragma unroll
      for (int nt = 0; nt < 2; ++nt)
        acc[rt][nt] = __builtin_amdgcn_mfma_f32_16x16x32_bf16(
            afrag, bfrag[nt][kk], acc[rt][nt], 0, 0, 0);
    }

#pragma unroll
  for (int rt = 0; rt < 4; ++rt)
#pragma unroll
    for (int nt = 0; nt < 2; ++nt)
#pragma unroll
      for (int i = 0; i < 4; ++i) {
        const int r = rt * 16 + lg * 4 + i;
        if (r < nrows)
          Gb[(size_t)(row0 + r) * DIM + col0 + nt * 16 + lr] =
              f2bf(acc[rt][nt][i]);
      }
}

// ---------------------------------------------------------------------------
// Kernel C: cooperative gather. 32-lane group per row l; within a group,
// 8 lanes (chunk c=lane&7) cooperate per neighbor; 4 neighbors/batch x 8.
// Each vmem gather instr touches 4 lines/group (vs 32 naive). Partial dots
// reduce over the 8-lane chunk group; sims land in LDS; per-lane-k softmax.
// ---------------------------------------------------------------------------
__global__ __launch_bounds__(256) void attn_kernel(
    const unsigned short* __restrict__ Gb, const unsigned char* __restrict__ Hb8,
    const float* __restrict__ mixp, const float* __restrict__ knn_w,
    const int* __restrict__ knn_idx,
    float* __restrict__ vals, float* __restrict__ rows,
    float* __restrict__ cols) {
  __shared__ float sims[8][KNN];
  const int tid = threadIdx.x;
  const int k = tid & 31;          // neighbor slot owned for softmax phase
  const int rg = tid >> 5;         // row group 0..7
  const int l = blockIdx.x * 8 + rg;
  const int o = l * KNN + k;

  const int idx_own = knn_idx[o];
  const float w_in = knn_w[o];

  const int c = tid & 7;           // 16-elem chunk of the 128-dim row
  const int nsub = (tid >> 3) & 3; // neighbor-within-batch

  // G[l] segment for chunk c: 16 bf16 -> 16 f32 regs (loaded once).
  const s8v ga = *(const s8v*)(Gb + (size_t)l * DIM + c * 16);
  const s8v gbv = *(const s8v*)(Gb + (size_t)l * DIM + c * 16 + 8);
  float gf[16];
#pragma unroll
  for (int j = 0; j < 8; ++j) { gf[j] = bf2f(ga[j]); gf[8 + j] = bf2f(gbv[j]); }

#pragma unroll
  for (int b = 0; b < 8; ++b) {
    const int j = b * 4 + nsub;                    // neighbor index 0..31
    const int idxn = __shfl(idx_own, j, 32);
    const i32x4 c4 = *(const i32x4*)(Hb8 + (size_t)idxn * DIM + c * 16);
    float p = 0.f;
#pragma unroll
    for (int d = 0; d < 4; ++d) {
      const f32x2 lo = __builtin_amdgcn_cvt_pk_f32_fp8((unsigned)c4[d], false);
      const f32x2 hi = __builtin_amdgcn_cvt_pk_f32_fp8((unsigned)c4[d], true);
      p = fmaf(gf[4 * d + 0], lo[0], p);
      p = fmaf(gf[4 * d + 1], lo[1], p);
      p = fmaf(gf[4 * d + 2], hi[0], p);
      p = fmaf(gf[4 * d + 3], hi[1], p);
    }
    // reduce across the 8 chunk lanes (consecutive lanes, xor 1/2/4)
    p += __shfl_xor(p, 1, 32);
    p += __shfl_xor(p, 2, 32);
    p += __shfl_xor(p, 4, 32);
    if (c == 0) sims[rg][j] = p;
  }
  // writer and readers are the same wave: compiler-inserted lgkmcnt suffices

  const float sim = sims[rg][k] * TAU_INV;

  float m = sim;
#pragma unroll
  for (int off = 16; off > 0; off >>= 1)
    m = fmaxf(m, __shfl_xor(m, off, 32));
  const float e = expf(sim - m);
  float s = e;
#pragma unroll
  for (int off = 16; off > 0; off >>= 1)
    s += __shfl_xor(s, off, 32);
  const float A = e / s;

  const float beta = 1.0f / (1.0f + expf(-mixp[0]));
  float w = (1.0f - beta) * w_in + beta * A;
  float ws = w;
#pragma unroll
  for (int off = 16; off > 0; off >>= 1)
    ws += __shfl_xor(ws, off, 32);
  const float v = w / (ws + EPS_NORM);

  __builtin_nontemporal_store(v, &vals[o]);
  __builtin_nontemporal_store((float)l, &rows[o]);
  __builtin_nontemporal_store((float)idx_own, &cols[o]);
}

extern "C" void kernel_launch(void* const* d_in, const int* in_sizes, int n_in,
                              void* d_out, int out_size, void* d_ws, size_t ws_size,
                              hipStream_t stream) {
  const float* H = (const float*)d_in[0];
  const float* Wq = (const float*)d_in[1];
  const float* Wk = (const float*)d_in[2];
  const float* mix = (const float*)d_in[3];
  const float* knn_w = (const float*)d_in[4];
  const int* knn_idx = (const int*)d_in[5];

  unsigned char* Hb8 = (unsigned char*)d_ws;                          // 6.4 MB
  unsigned short* Gb =
      (unsigned short*)((char*)d_ws + (size_t)LROWS * DIM);           // 12.8 MB
  unsigned short* Mt =
      (unsigned short*)((char*)d_ws + (size_t)LROWS * DIM * 3);       // 32 KB

  float* out = (float*)d_out;
  float* vals = out;
  float* rowsp = out + (size_t)LROWS * KNN;
  float* colsp = out + 2 * (size_t)LROWS * KNN;

  mmat_kernel<<<DIM, DIM, 0, stream>>>(Wq, Wk, Mt);
  proj_kernel<<<(LROWS + 63) / 64, 256, 0, stream>>>(H, Mt, Gb, Hb8);
  attn_kernel<<<LROWS / 8, 256, 0, stream>>>(Gb, Hb8, mix, knn_w, knn_idx,
                                             vals, rowsp, colsp);
}

// Round 9
// 122.315 us; speedup vs baseline: 1.5890x; 1.0341x over previous
//
#include <hip/hip_runtime.h>
#include <hip/hip_bf16.h>

#define LROWS 50000
#define KNN 32
#define DIM 128
#define TAU_INV 5.0f
#define EPS_NORM 1e-8f
#define ROWSTR 136  // proj LDS row stride in shorts (272 B): 2-way bank alias only

typedef short s8v __attribute__((ext_vector_type(8)));
typedef float f32x4 __attribute__((ext_vector_type(4)));
typedef float f32x2 __attribute__((ext_vector_type(2)));
typedef int i32x2 __attribute__((ext_vector_type(2)));
typedef int i32x4 __attribute__((ext_vector_type(4)));

__device__ __forceinline__ unsigned short f2bf(float f) {
  union { float f; unsigned u; } v; v.f = f;
  unsigned r = v.u + 0x7FFFu + ((v.u >> 16) & 1u);
  return (unsigned short)(r >> 16);
}
__device__ __forceinline__ float bf2f(short s) {
  union { unsigned u; float f; } v;
  v.u = ((unsigned)(unsigned short)s) << 16;
  return v.f;
}

// ---------------------------------------------------------------------------
// Kernel A: Mt[c][k] = (Wq^T Wk)^T[c][k] = sum_j Wk[j][c] * Wq[j][k], bf16.
// ---------------------------------------------------------------------------
__global__ __launch_bounds__(128) void mmat_kernel(
    const float* __restrict__ Wq, const float* __restrict__ Wk,
    unsigned short* __restrict__ Mt) {
  const int c = blockIdx.x;
  const int k = threadIdx.x;
  float acc = 0.f;
#pragma unroll 8
  for (int j = 0; j < DIM; ++j)
    acc = fmaf(Wk[j * DIM + c], Wq[j * DIM + k], acc);
  Mt[c * DIM + k] = f2bf(acc);
}

// ---------------------------------------------------------------------------
// Kernel B: Gb = bf16(H @ M) via MFMA 16x16x32 bf16; emits Hb8 = fp8_e4m3(H).
// Block = 256 thr (4 waves), 64 H-rows staged bf16 in LDS (padded rows).
// ---------------------------------------------------------------------------
__global__ __launch_bounds__(256) void proj_kernel(
    const float* __restrict__ H, const unsigned short* __restrict__ Mt,
    unsigned short* __restrict__ Gb, unsigned char* __restrict__ Hb8) {
  __shared__ short Hs[64 * ROWSTR];
  const int tid = threadIdx.x;
  const int row0 = blockIdx.x * 64;
  const int nrows = min(64, LROWS - row0);

#pragma unroll
  for (int i = 0; i < 4; ++i) {
    const int cid = i * 256 + tid;   // 1024 chunks of 8 elems
    const int r = cid >> 4;          // local row 0..63
    const int cc = (cid & 15) * 8;   // col 0..120
    const int gr = (r < nrows) ? r : 0;
    const float4* src = (const float4*)(H + (size_t)(row0 + gr) * DIM + cc);
    const float4 a = src[0], b = src[1];
    s8v p;
    p[0] = (short)f2bf(a.x); p[1] = (short)f2bf(a.y);
    p[2] = (short)f2bf(a.z); p[3] = (short)f2bf(a.w);
    p[4] = (short)f2bf(b.x); p[5] = (short)f2bf(b.y);
    p[6] = (short)f2bf(b.z); p[7] = (short)f2bf(b.w);
    *(s8v*)&Hs[r * ROWSTR + cc] = p;
    if (r < nrows) {
      unsigned d0 = 0, d1 = 0;
      d0 = __builtin_amdgcn_cvt_pk_fp8_f32(a.x, a.y, d0, false);
      d0 = __builtin_amdgcn_cvt_pk_fp8_f32(a.z, a.w, d0, true);
      d1 = __builtin_amdgcn_cvt_pk_fp8_f32(b.x, b.y, d1, false);
      d1 = __builtin_amdgcn_cvt_pk_fp8_f32(b.z, b.w, d1, true);
      i32x2 pk; pk[0] = (int)d0; pk[1] = (int)d1;
      *(i32x2*)(Hb8 + (size_t)(row0 + r) * DIM + cc) = pk;
    }
  }
  __syncthreads();

  const int lane = tid & 63;
  const int wv = tid >> 6;
  const int col0 = wv * 32;
  const int lr = lane & 15;
  const int lg = lane >> 4;

  s8v bfrag[2][4];
#pragma unroll
  for (int nt = 0; nt < 2; ++nt)
#pragma unroll
    for (int kk = 0; kk < 4; ++kk)
      bfrag[nt][kk] =
          *(const s8v*)(Mt + (size_t)(col0 + nt * 16 + lr) * DIM + kk * 32 + lg * 8);

  f32x4 acc[4][2];
#pragma unroll
  for (int rt = 0; rt < 4; ++rt)
#pragma unroll
    for (int nt = 0; nt < 2; ++nt)
      acc[rt][nt] = (f32x4){0.f, 0.f, 0.f, 0.f};

#pragma unroll
  for (int rt = 0; rt < 4; ++rt)
#pragma unroll
    for (int kk = 0; kk < 4; ++kk) {
      const s8v afrag =
          *(const s8v*)&Hs[(rt * 16 + lr) * ROWSTR + kk * 32 + lg * 8];
#pragma unroll
      for (int nt = 0; nt < 2; ++nt)
        acc[rt][nt] = __builtin_amdgcn_mfma_f32_16x16x32_bf16(
            afrag, bfrag[nt][kk], acc[rt][nt], 0, 0, 0);
    }

#pragma unroll
  for (int rt = 0; rt < 4; ++rt)
#pragma unroll
    for (int nt = 0; nt < 2; ++nt)
#pragma unroll
      for (int i = 0; i < 4; ++i) {
        const int r = rt * 16 + lg * 4 + i;
        if (r < nrows)
          Gb[(size_t)(row0 + r) * DIM + col0 + nt * 16 + lr] =
              f2bf(acc[rt][nt][i]);
      }
}

// ---------------------------------------------------------------------------
// Kernel C: cooperative gather, explicit 8-deep load pipeline.
// 32-lane group per row l; 8 lanes (chunk c) cooperate per neighbor;
// all 8 gather loads issued before any decode/FMA (8 outstanding vmem/lane).
// Streamed tensors (Gb, knn) use nontemporal loads to keep Hb8 L2-resident.
// ---------------------------------------------------------------------------
__global__ __launch_bounds__(256) void attn_kernel(
    const unsigned short* __restrict__ Gb, const unsigned char* __restrict__ Hb8,
    const float* __restrict__ mixp, const float* __restrict__ knn_w,
    const int* __restrict__ knn_idx,
    float* __restrict__ vals, float* __restrict__ rows,
    float* __restrict__ cols) {
  __shared__ float sims[8][KNN];
  const int tid = threadIdx.x;
  const int k = tid & 31;          // neighbor slot owned in softmax phase
  const int rg = tid >> 5;         // row group 0..7
  const int l = blockIdx.x * 8 + rg;
  const int o = l * KNN + k;

  const int idx_own = __builtin_nontemporal_load(&knn_idx[o]);
  const float w_in = __builtin_nontemporal_load(&knn_w[o]);

  const int c = tid & 7;           // 16-elem chunk of the 128-dim row
  const int nsub = (tid >> 3) & 3; // neighbor-within-batch

  // All 8 neighbor indices for this lane's (nsub, batches 0..7).
  int idxn[8];
#pragma unroll
  for (int b = 0; b < 8; ++b) idxn[b] = __shfl(idx_own, b * 4 + nsub, 32);

  // Issue all 8 gathers up front (8 outstanding 16B loads per lane).
  i32x4 c4[8];
#pragma unroll
  for (int b = 0; b < 8; ++b)
    c4[b] = *(const i32x4*)(Hb8 + (size_t)idxn[b] * DIM + c * 16);

  // G[l] chunk: 16 bf16 -> 16 f32 regs (nontemporal: don't evict Hb8).
  const s8v ga = __builtin_nontemporal_load(
      (const s8v*)(Gb + (size_t)l * DIM + c * 16));
  const s8v gbv = __builtin_nontemporal_load(
      (const s8v*)(Gb + (size_t)l * DIM + c * 16 + 8));
  float gf[16];
#pragma unroll
  for (int j = 0; j < 8; ++j) { gf[j] = bf2f(ga[j]); gf[8 + j] = bf2f(gbv[j]); }

#pragma unroll
  for (int b = 0; b < 8; ++b) {
    const int j = b * 4 + nsub;
    float p = 0.f;
#pragma unroll
    for (int d = 0; d < 4; ++d) {
      const f32x2 lo = __builtin_amdgcn_cvt_pk_f32_fp8((unsigned)c4[b][d], false);
      const f32x2 hi = __builtin_amdgcn_cvt_pk_f32_fp8((unsigned)c4[b][d], true);
      p = fmaf(gf[4 * d + 0], lo[0], p);
      p = fmaf(gf[4 * d + 1], lo[1], p);
      p = fmaf(gf[4 * d + 2], hi[0], p);
      p = fmaf(gf[4 * d + 3], hi[1], p);
    }
    p += __shfl_xor(p, 1, 32);
    p += __shfl_xor(p, 2, 32);
    p += __shfl_xor(p, 4, 32);
    if (c == 0) sims[rg][j] = p;
  }
  // writer and readers are the same wave: compiler-inserted lgkmcnt suffices

  const float sim = sims[rg][k] * TAU_INV;

  float m = sim;
#pragma unroll
  for (int off = 16; off > 0; off >>= 1)
    m = fmaxf(m, __shfl_xor(m, off, 32));
  const float e = expf(sim - m);
  float s = e;
#pragma unroll
  for (int off = 16; off > 0; off >>= 1)
    s += __shfl_xor(s, off, 32);
  const float A = e / s;

  const float beta = 1.0f / (1.0f + expf(-mixp[0]));
  float w = (1.0f - beta) * w_in + beta * A;
  float ws = w;
#pragma unroll
  for (int off = 16; off > 0; off >>= 1)
    ws += __shfl_xor(ws, off, 32);
  const float v = w / (ws + EPS_NORM);

  __builtin_nontemporal_store(v, &vals[o]);
  __builtin_nontemporal_store((float)l, &rows[o]);
  __builtin_nontemporal_store((float)idx_own, &cols[o]);
}

extern "C" void kernel_launch(void* const* d_in, const int* in_sizes, int n_in,
                              void* d_out, int out_size, void* d_ws, size_t ws_size,
                              hipStream_t stream) {
  const float* H = (const float*)d_in[0];
  const float* Wq = (const float*)d_in[1];
  const float* Wk = (const float*)d_in[2];
  const float* mix = (const float*)d_in[3];
  const float* knn_w = (const float*)d_in[4];
  const int* knn_idx = (const int*)d_in[5];

  unsigned char* Hb8 = (unsigned char*)d_ws;                          // 6.4 MB
  unsigned short* Gb =
      (unsigned short*)((char*)d_ws + (size_t)LROWS * DIM);           // 12.8 MB
  unsigned short* Mt =
      (unsigned short*)((char*)d_ws + (size_t)LROWS * DIM * 3);       // 32 KB

  float* out = (float*)d_out;
  float* vals = out;
  float* rowsp = out + (size_t)LROWS * KNN;
  float* colsp = out + 2 * (size_t)LROWS * KNN;

  mmat_kernel<<<DIM, DIM, 0, stream>>>(Wq, Wk, Mt);
  proj_kernel<<<(LROWS + 63) / 64, 256, 0, stream>>>(H, Mt, Gb, Hb8);
  attn_kernel<<<LROWS / 8, 256, 0, stream>>>(Gb, Hb8, mix, knn_w, knn_idx,
                                             vals, rowsp, colsp);
}

// Round 10
// 121.222 us; speedup vs baseline: 1.6033x; 1.0090x over previous
//
#include <hip/hip_runtime.h>
#include <hip/hip_bf16.h>

#define LROWS 50000
#define KNN 32
#define DIM 128
#define TAU_INV 5.0f
#define EPS_NORM 1e-8f
#define ROWSTR 136      // proj LDS row stride in shorts (272 B)
#define SCALE4 0.53333333f   // 4.0 / 7.5 : int4 step
#define INV_SCALE4 1.875f    // 7.5 / 4.0

typedef short s8v __attribute__((ext_vector_type(8)));
typedef float f32x4 __attribute__((ext_vector_type(4)));
typedef int i32x2 __attribute__((ext_vector_type(2)));

__device__ __forceinline__ unsigned short f2bf(float f) {
  union { float f; unsigned u; } v; v.f = f;
  unsigned r = v.u + 0x7FFFu + ((v.u >> 16) & 1u);
  return (unsigned short)(r >> 16);
}
__device__ __forceinline__ float bf2f(short s) {
  union { unsigned u; float f; } v;
  v.u = ((unsigned)(unsigned short)s) << 16;
  return v.f;
}
__device__ __forceinline__ unsigned pack4(const float* e) {
  unsigned pk = 0;
#pragma unroll
  for (int n = 0; n < 8; ++n) {
    float t = rintf(e[n] * INV_SCALE4);
    t = fminf(7.f, fmaxf(-8.f, t));
    pk |= (((unsigned)(int)(t + 8.f)) & 15u) << (4 * n);
  }
  return pk;
}

// ---------------------------------------------------------------------------
// Kernel A: Mt[c][k] = (Wq^T Wk)^T[c][k] = sum_j Wk[j][c] * Wq[j][k], bf16.
// ---------------------------------------------------------------------------
__global__ __launch_bounds__(128) void mmat_kernel(
    const float* __restrict__ Wq, const float* __restrict__ Wk,
    unsigned short* __restrict__ Mt) {
  const int c = blockIdx.x;
  const int k = threadIdx.x;
  float acc = 0.f;
#pragma unroll 8
  for (int j = 0; j < DIM; ++j)
    acc = fmaf(Wk[j * DIM + c], Wq[j * DIM + k], acc);
  Mt[c * DIM + k] = f2bf(acc);
}

// ---------------------------------------------------------------------------
// Kernel B: Gb = bf16(H @ M) via MFMA 16x16x32 bf16; emits Hq4 = int4(H).
// Hq4 row = 128 nibbles = 16 dwords = 64 B; table total 3.2 MB (L2-resident).
// ---------------------------------------------------------------------------
__global__ __launch_bounds__(256) void proj_kernel(
    const float* __restrict__ H, const unsigned short* __restrict__ Mt,
    unsigned short* __restrict__ Gb, unsigned* __restrict__ Hq4) {
  __shared__ short Hs[64 * ROWSTR];
  const int tid = threadIdx.x;
  const int row0 = blockIdx.x * 64;
  const int nrows = min(64, LROWS - row0);

#pragma unroll
  for (int i = 0; i < 4; ++i) {
    const int cid = i * 256 + tid;   // 1024 chunks of 8 elems
    const int r = cid >> 4;          // local row 0..63
    const int cc = (cid & 15) * 8;   // col 0..120
    const int gr = (r < nrows) ? r : 0;
    const float4* src = (const float4*)(H + (size_t)(row0 + gr) * DIM + cc);
    const float4 a = src[0], b = src[1];
    s8v p;
    p[0] = (short)f2bf(a.x); p[1] = (short)f2bf(a.y);
    p[2] = (short)f2bf(a.z); p[3] = (short)f2bf(a.w);
    p[4] = (short)f2bf(b.x); p[5] = (short)f2bf(b.y);
    p[6] = (short)f2bf(b.z); p[7] = (short)f2bf(b.w);
    *(s8v*)&Hs[r * ROWSTR + cc] = p;
    if (r < nrows) {
      const float e[8] = {a.x, a.y, a.z, a.w, b.x, b.y, b.z, b.w};
      Hq4[(size_t)(row0 + r) * 16 + (cid & 15)] = pack4(e);
    }
  }
  __syncthreads();

  const int lane = tid & 63;
  const int wv = tid >> 6;
  const int col0 = wv * 32;
  const int lr = lane & 15;
  const int lg = lane >> 4;

  s8v bfrag[2][4];
#pragma unroll
  for (int nt = 0; nt < 2; ++nt)
#pragma unroll
    for (int kk = 0; kk < 4; ++kk)
      bfrag[nt][kk] =
          *(const s8v*)(Mt + (size_t)(col0 + nt * 16 + lr) * DIM + kk * 32 + lg * 8);

  f32x4 acc[4][2];
#pragma unroll
  for (int rt = 0; rt < 4; ++rt)
#pragma unroll
    for (int nt = 0; nt < 2; ++nt)
      acc[rt][nt] = (f32x4){0.f, 0.f, 0.f, 0.f};

#pragma unroll
  for (int rt = 0; rt < 4; ++rt)
#pragma unroll
    for (int kk = 0; kk < 4; ++kk) {
      const s8v afrag =
          *(const s8v*)&Hs[(rt * 16 + lr) * ROWSTR + kk * 32 + lg * 8];
#pragma unroll
      for (int nt = 0; nt < 2; ++nt)
        acc[rt][nt] = __builtin_amdgcn_mfma_f32_16x16x32_bf16(
            afrag, bfrag[nt][kk], acc[rt][nt], 0, 0, 0);
    }

#pragma unroll
  for (int rt = 0; rt < 4; ++rt)
#pragma unroll
    for (int nt = 0; nt < 2; ++nt)
#pragma unroll
      for (int i = 0; i < 4; ++i) {
        const int r = rt * 16 + lg * 4 + i;
        if (r < nrows)
          Gb[(size_t)(row0 + r) * DIM + col0 + nt * 16 + lr] =
              f2bf(acc[rt][nt][i]);
      }
}

// ---------------------------------------------------------------------------
// Kernel C: cooperative int4 gather. 32-lane group per row l; 8 lanes per
// neighbor (8 B each); all 8 gathers issued up front. Decode: bfe+cvt+fma,
// sim_chunk = SCALE4 * (sum g*nib - 8*sum g). Streams NT to protect L2 table.
// ---------------------------------------------------------------------------
__global__ __launch_bounds__(256) void attn_kernel(
    const unsigned short* __restrict__ Gb, const unsigned* __restrict__ Hq4,
    const float* __restrict__ mixp, const float* __restrict__ knn_w,
    const int* __restrict__ knn_idx,
    float* __restrict__ vals, float* __restrict__ rows,
    float* __restrict__ cols) {
  __shared__ float sims[8][KNN];
  const int tid = threadIdx.x;
  const int k = tid & 31;          // neighbor slot owned in softmax phase
  const int rg = tid >> 5;         // row group 0..7
  const int l = blockIdx.x * 8 + rg;
  const int o = l * KNN + k;

  const int idx_own = __builtin_nontemporal_load(&knn_idx[o]);
  const float w_in = __builtin_nontemporal_load(&knn_w[o]);

  const int c = tid & 7;           // 16-elem chunk of the 128-dim row
  const int nsub = (tid >> 3) & 3; // neighbor-within-batch

  int idxn[8];
#pragma unroll
  for (int b = 0; b < 8; ++b) idxn[b] = __shfl(idx_own, b * 4 + nsub, 32);

  // Issue all 8 gathers up front (8 B each: 2 dwords = 16 nibbles).
  i32x2 d4[8];
#pragma unroll
  for (int b = 0; b < 8; ++b)
    d4[b] = *(const i32x2*)(Hq4 + (size_t)idxn[b] * 16 + c * 2);

  // G[l] chunk: 16 bf16 -> 16 f32 regs (nontemporal: don't evict table).
  const s8v ga = __builtin_nontemporal_load(
      (const s8v*)(Gb + (size_t)l * DIM + c * 16));
  const s8v gbv = __builtin_nontemporal_load(
      (const s8v*)(Gb + (size_t)l * DIM + c * 16 + 8));
  float gf[16];
  float sumg = 0.f;
#pragma unroll
  for (int j = 0; j < 8; ++j) { gf[j] = bf2f(ga[j]); gf[8 + j] = bf2f(gbv[j]); }
#pragma unroll
  for (int j = 0; j < 16; ++j) sumg += gf[j];

#pragma unroll
  for (int b = 0; b < 8; ++b) {
    const int j = b * 4 + nsub;
    float acc = 0.f;
#pragma unroll
    for (int w = 0; w < 2; ++w) {
      const unsigned dw = (unsigned)d4[b][w];
#pragma unroll
      for (int n = 0; n < 8; ++n)
        acc = fmaf(gf[w * 8 + n], (float)((dw >> (4 * n)) & 15u), acc);
    }
    float p = (acc - 8.f * sumg) * SCALE4;
    p += __shfl_xor(p, 1, 32);
    p += __shfl_xor(p, 2, 32);
    p += __shfl_xor(p, 4, 32);
    if (c == 0) sims[rg][j] = p;
  }
  // writers and readers are the same wave: compiler-inserted lgkmcnt suffices

  const float sim = sims[rg][k] * TAU_INV;

  float m = sim;
#pragma unroll
  for (int off = 16; off > 0; off >>= 1)
    m = fmaxf(m, __shfl_xor(m, off, 32));
  const float e = expf(sim - m);
  float s = e;
#pragma unroll
  for (int off = 16; off > 0; off >>= 1)
    s += __shfl_xor(s, off, 32);
  const float A = e / s;

  const float beta = 1.0f / (1.0f + expf(-mixp[0]));
  float w = (1.0f - beta) * w_in + beta * A;
  float ws = w;
#pragma unroll
  for (int off = 16; off > 0; off >>= 1)
    ws += __shfl_xor(ws, off, 32);
  const float v = w / (ws + EPS_NORM);

  __builtin_nontemporal_store(v, &vals[o]);
  __builtin_nontemporal_store((float)l, &rows[o]);
  __builtin_nontemporal_store((float)idx_own, &cols[o]);
}

extern "C" void kernel_launch(void* const* d_in, const int* in_sizes, int n_in,
                              void* d_out, int out_size, void* d_ws, size_t ws_size,
                              hipStream_t stream) {
  const float* H = (const float*)d_in[0];
  const float* Wq = (const float*)d_in[1];
  const float* Wk = (const float*)d_in[2];
  const float* mix = (const float*)d_in[3];
  const float* knn_w = (const float*)d_in[4];
  const int* knn_idx = (const int*)d_in[5];

  unsigned* Hq4 = (unsigned*)d_ws;                                  // 3.2 MB
  unsigned short* Gb =
      (unsigned short*)((char*)d_ws + (size_t)LROWS * 64);          // 12.8 MB
  unsigned short* Mt =
      (unsigned short*)((char*)d_ws + (size_t)LROWS * 64 +
                        (size_t)LROWS * DIM * 2);                   // 32 KB

  float* out = (float*)d_out;
  float* vals = out;
  float* rowsp = out + (size_t)LROWS * KNN;
  float* colsp = out + 2 * (size_t)LROWS * KNN;

  mmat_kernel<<<DIM, DIM, 0, stream>>>(Wq, Wk, Mt);
  proj_kernel<<<(LROWS + 63) / 64, 256, 0, stream>>>(H, Mt, Gb, Hq4);
  attn_kernel<<<LROWS / 8, 256, 0, stream>>>(Gb, Hq4, mix, knn_w, knn_idx,
                                             vals, rowsp, colsp);
}